// Round 2
// baseline (1114.912 us; speedup 1.0000x reference)
//
#include <hip/hip_runtime.h>
#include <float.h>
#include <math.h>

#define DIM    128
#define KCB    8192
#define BT     128     // tokens per block
#define BC     128     // codes per chunk
#define LP     132     // LDS row pitch (floats): 132*4=528B -> float4 aligned, bank-stride 4
#define NCHUNK (KCB / BC)

// ---------------- kernel 1: h_k = 0.5*|e_k|^2, zero counts/loss ----------------
__global__ __launch_bounds__(256) void vq_prep(
    const float* __restrict__ emb, float* __restrict__ h,
    unsigned* __restrict__ counts, double* __restrict__ loss)
{
    const int tid = threadIdx.x;
    const int gid = blockIdx.x * 256 + tid;
    if (gid < KCB) counts[gid] = 0u;
    if (gid == 0) *loss = 0.0;
    const int code = gid >> 6;          // one wave (64 lanes) per code
    const int lane = tid & 63;
    if (code < KCB) {
        const float2* e2 = (const float2*)(emb + (size_t)code * DIM);
        float2 v = e2[lane];            // coalesced: 64 lanes * 8B = one row
        float s = v.x * v.x + v.y * v.y;
        #pragma unroll
        for (int o = 32; o > 0; o >>= 1) s += __shfl_down(s, o);
        if (lane == 0) h[code] = 0.5f * s;
    }
}

// ---------------- kernel 2: fused distance-GEMM + argmin + gather + loss ----------------
__global__ __launch_bounds__(256, 1) void vq_main(
    const float* __restrict__ z, const float* __restrict__ emb,
    const float* __restrict__ h, unsigned* __restrict__ counts,
    double* __restrict__ loss, float* __restrict__ out)
{
    __shared__ float zs[BT * LP];       // 67584 B, [token][d]
    __shared__ float es[BC * LP];       // 67584 B, [code][d]  (reused for final reduce)
    __shared__ int   idx_sh[BT];
    __shared__ double wred[4];

    const int tid = threadIdx.x;
    const int tx  = tid & 15;           // code-thread
    const int ty  = tid >> 4;           // token-thread
    const long t0 = (long)blockIdx.x * BT;

    // ---- stage z tile, flat-linear (fully coalesced global reads) ----
    {
        const float4* zf4 = (const float4*)(z + t0 * DIM);
        #pragma unroll
        for (int m = 0; m < 16; ++m) {
            int f = m * 256 + tid;              // float4 index in 128x128 tile
            float4 v = zf4[f];
            int t = f >> 5, d0 = (f & 31) << 2;
            *(float4*)&zs[t * LP + d0] = v;
        }
    }

    int zbase[8], ebase[8];
    #pragma unroll
    for (int i = 0; i < 8; ++i) {
        zbase[i] = (ty + 16 * i) * LP;          // tokens ty+16*tt (16-way broadcast reads)
        ebase[i] = (tx + 16 * i) * LP;          // codes  tx+16*j  (2-way alias: free)
    }

    float bv[8]; int bi[8];
    #pragma unroll
    for (int i = 0; i < 8; ++i) { bv[i] = FLT_MAX; bi[i] = 0; }

    for (int ch = 0; ch < NCHUNK; ++ch) {
        const int cb = ch * BC;
        __syncthreads();                        // prior chunk's compute done before es overwrite
        {
            const float4* ef4 = (const float4*)(emb + (size_t)cb * DIM);
            #pragma unroll
            for (int m = 0; m < 16; ++m) {
                int f = m * 256 + tid;
                float4 v = ef4[f];
                int k = f >> 5, d0 = (f & 31) << 2;
                *(float4*)&es[k * LP + d0] = v;
            }
        }
        float hv[8];
        #pragma unroll
        for (int j = 0; j < 8; ++j) hv[j] = h[cb + tx + 16 * j];
        __syncthreads();

        float acc[8][8];
        #pragma unroll
        for (int a = 0; a < 8; ++a)
            #pragma unroll
            for (int b = 0; b < 8; ++b) acc[a][b] = 0.f;

        #pragma unroll 2
        for (int d0 = 0; d0 < DIM; d0 += 4) {
            float4 zv[8], ev[8];
            #pragma unroll
            for (int i = 0; i < 8; ++i) zv[i] = *(const float4*)&zs[zbase[i] + d0];
            #pragma unroll
            for (int j = 0; j < 8; ++j) ev[j] = *(const float4*)&es[ebase[j] + d0];
            #pragma unroll
            for (int i = 0; i < 8; ++i)
                #pragma unroll
                for (int j = 0; j < 8; ++j) {
                    acc[i][j] = fmaf(zv[i].x, ev[j].x, acc[i][j]);
                    acc[i][j] = fmaf(zv[i].y, ev[j].y, acc[i][j]);
                    acc[i][j] = fmaf(zv[i].z, ev[j].z, acc[i][j]);
                    acc[i][j] = fmaf(zv[i].w, ev[j].w, acc[i][j]);
                }
        }

        // running argmin: score = 0.5|e|^2 - z.e  (monotone in true sq-distance)
        #pragma unroll
        for (int i = 0; i < 8; ++i)
            #pragma unroll
            for (int j = 0; j < 8; ++j) {
                float sc = hv[j] - acc[i][j];
                int   c  = cb + tx + 16 * j;
                if (sc < bv[i]) { bv[i] = sc; bi[i] = c; }   // strict <: keeps lowest index
            }
    }

    // ---- cross-thread argmin reduce (16 code-threads per token), overlay on es ----
    __syncthreads();
    float* red_v = es;                      // [BT][16]
    int*   red_i = (int*)(es + BT * 16);    // [BT][16]
    #pragma unroll
    for (int i = 0; i < 8; ++i) {
        int t = ty + 16 * i;
        red_v[t * 16 + tx] = bv[i];
        red_i[t * 16 + tx] = bi[i];
    }
    __syncthreads();
    if (tid < BT) {
        float best = red_v[tid * 16];
        int   bidx = red_i[tid * 16];
        #pragma unroll
        for (int x = 1; x < 16; ++x) {
            float v = red_v[tid * 16 + x];
            int   i = red_i[tid * 16 + x];
            if (v < best || (v == best && i < bidx)) { best = v; bidx = i; }
        }
        idx_sh[tid] = bidx;
        atomicAdd(&counts[bidx], 1u);
    }
    __syncthreads();

    // ---- gather z_q, straight-through output z + (z_q - z), loss partial ----
    float lsum = 0.f;
    {
        const float4* ef4 = (const float4*)emb;
        float4* of4 = (float4*)(out + t0 * DIM);
        #pragma unroll
        for (int m = 0; m < 16; ++m) {
            int f = m * 256 + tid;
            int t = f >> 5, dw = f & 31;
            int ci = idx_sh[t];
            float4 e4 = ef4[(size_t)ci * 32 + dw];
            float4 z4 = *(const float4*)&zs[t * LP + (dw << 2)];
            float dx = e4.x - z4.x, dy = e4.y - z4.y;
            float dz = e4.z - z4.z, dw2 = e4.w - z4.w;
            lsum += dx * dx + dy * dy + dz * dz + dw2 * dw2;
            float4 o;
            o.x = z4.x + dx; o.y = z4.y + dy; o.z = z4.z + dz; o.w = z4.w + dw2;
            of4[f] = o;     // coalesced; replicates reference rounding z + (zq - z)
        }
    }
    #pragma unroll
    for (int o = 32; o > 0; o >>= 1) lsum += __shfl_down(lsum, o);
    if ((tid & 63) == 0) wred[tid >> 6] = (double)lsum;
    __syncthreads();
    if (tid == 0) atomicAdd(loss, wred[0] + wred[1] + wred[2] + wred[3]);
}

// ---------------- kernel 3: perplexity + final commit loss ----------------
__global__ __launch_bounds__(256) void vq_final(
    const unsigned* __restrict__ counts, const double* __restrict__ loss,
    float* __restrict__ out, int n_elems, int n_tok)
{
    __shared__ double sh[4];
    const int tid = threadIdx.x;
    double s = 0.0;
    for (int i = tid; i < KCB; i += 256) {
        float em = (float)counts[i] / (float)n_tok;
        s += (double)(em * logf(em + 1e-8f));
    }
    #pragma unroll
    for (int o = 32; o > 0; o >>= 1) s += __shfl_down(s, o);
    if ((tid & 63) == 0) sh[tid >> 6] = s;
    __syncthreads();
    if (tid == 0) {
        double tot = sh[0] + sh[1] + sh[2] + sh[3];
        out[(size_t)n_elems]     = (float)(1.25 * loss[0] / (double)n_elems); // 0.25*m + m
        out[(size_t)n_elems + 1] = expf((float)(-tot));
    }
}

extern "C" void kernel_launch(void* const* d_in, const int* in_sizes, int n_in,
                              void* d_out, int out_size, void* d_ws, size_t ws_size,
                              hipStream_t stream)
{
    const float* z   = (const float*)d_in[0];
    const float* emb = (const float*)d_in[1];
    float* out = (float*)d_out;

    float*    h      = (float*)d_ws;                                   // 32 KB
    unsigned* counts = (unsigned*)((char*)d_ws + KCB * sizeof(float)); // 32 KB
    double*   loss   = (double*)((char*)d_ws + 2 * KCB * sizeof(float));

    const int n_elems = in_sizes[0];        // 4194304
    const int ntok    = n_elems / DIM;      // 32768

    vq_prep <<<dim3(KCB / 4),   256, 0, stream>>>(emb, h, counts, loss);
    vq_main <<<dim3(ntok / BT), 256, 0, stream>>>(z, emb, h, counts, loss, out);
    vq_final<<<dim3(1),         256, 0, stream>>>(counts, loss, out, n_elems, ntok);
}

// Round 3
// 263.549 us; speedup vs baseline: 4.2304x; 4.2304x over previous
//
#include <hip/hip_runtime.h>
#include <float.h>
#include <math.h>

#define DIM    128
#define KCB    8192
#define BT     128               // tokens per block
#define NC     128               // codes per chunk
#define NCHUNK (KCB / NC)

typedef __attribute__((ext_vector_type(8))) short bf16x8;
typedef __attribute__((ext_vector_type(4))) float f32x4;

// persistent scratch as device globals (avoids ws_size assumptions; rewritten every call)
__device__ unsigned g_ehi[KCB * DIM / 2];   // 2 MB: packed bf16 pairs, XOR-swizzle pre-baked
__device__ unsigned g_elo[KCB * DIM / 2];   // 2 MB
__device__ float    g_h[KCB];
__device__ unsigned g_counts[KCB];
__device__ double   g_loss;

__device__ __forceinline__ unsigned short f2b(float x) {      // RNE fp32->bf16
    union { float f; unsigned u; } v; v.f = x;
    unsigned r = v.u + 0x7fffu + ((v.u >> 16) & 1u);
    return (unsigned short)(r >> 16);
}
__device__ __forceinline__ float b2f(unsigned short h) {
    union { unsigned u; float f; } v; v.u = ((unsigned)h) << 16; return v.f;
}
__device__ __forceinline__ void gll16(const void* g, void* l) {   // async global->LDS, 16B/lane
    __builtin_amdgcn_global_load_lds(
        (const __attribute__((address_space(1))) void*)g,
        (__attribute__((address_space(3))) void*)l, 16, 0, 0);
}

// ---------------- prep: split emb into bf16 hi/lo (swizzled), h_k, zero counts/loss ----------
__global__ __launch_bounds__(256) void vq_prep(const float* __restrict__ emb)
{
    const int tid  = threadIdx.x;
    const int gid  = blockIdx.x * 256 + tid;
    if (gid < KCB) g_counts[gid] = 0u;
    if (gid == 0)  g_loss = 0.0;

    const int code = (blockIdx.x << 2) + (tid >> 6);   // one wave per code
    const int lane = tid & 63;
    const float2 v = ((const float2*)emb)[code * 64 + lane];   // d = 2*lane, 2*lane+1

    unsigned short h0 = f2b(v.x), h1 = f2b(v.y);
    unsigned short l0 = f2b(v.x - b2f(h0)), l1 = f2b(v.y - b2f(h1));
    // packed16[k*128 + w] = e_bf[k][ w ^ ((k&7)<<3) ]  ->  word idx = lane ^ ((k&7)<<2)
    const int widx = code * 64 + (lane ^ ((code & 7) << 2));
    g_ehi[widx] = (unsigned)h0 | ((unsigned)h1 << 16);
    g_elo[widx] = (unsigned)l0 | ((unsigned)l1 << 16);

    float s = v.x * v.x + v.y * v.y;
    #pragma unroll
    for (int o = 32; o > 0; o >>= 1) s += __shfl_down(s, o);
    if (lane == 0) g_h[code] = 0.5f * s;
}

// ---------------- main: 3-pass bf16 MFMA distance GEMM + fused argmin + epilogue -------------
__global__ __launch_bounds__(512, 1) void vq_main(
    const float* __restrict__ z, const float* __restrict__ emb, float* __restrict__ out)
{
    __shared__ char   smem[2 * 65536];        // 2 bufs x (ehi 32KB | elo 32KB), swizzled rows
    __shared__ float  rv[BT * 2];
    __shared__ int    ri[BT * 2];
    __shared__ int    idx_sh[BT];
    __shared__ double wred[8];

    const int tid  = threadIdx.x;
    const int lane = tid & 63;
    const int wid  = tid >> 6;                // 8 waves
    const int tq   = wid & 3;                 // token quarter (32 tokens)
    const int ch2  = wid >> 2;                // code half (64 codes/chunk)
    const int l15  = lane & 15;
    const int lg   = lane >> 4;
    const long t0  = (long)blockIdx.x * BT;

    // ---- A fragments: z rows in registers for the whole kernel (hi + lo bf16 split) ----
    bf16x8 ah[2][4], al[2][4];
    #pragma unroll
    for (int m = 0; m < 2; ++m) {
        const long trow = t0 + tq * 32 + m * 16 + l15;
        #pragma unroll
        for (int kk = 0; kk < 4; ++kk) {
            const float4* zp = (const float4*)(z + trow * DIM + kk * 32 + lg * 8);
            float4 v0 = zp[0], v1 = zp[1];
            float xs[8] = {v0.x, v0.y, v0.z, v0.w, v1.x, v1.y, v1.z, v1.w};
            #pragma unroll
            for (int j = 0; j < 8; ++j) {
                unsigned short hb = f2b(xs[j]);
                ah[m][kk][j] = (short)hb;
                al[m][kk][j] = (short)f2b(xs[j] - b2f(hb));
            }
        }
    }

    // ---- per-lane swizzled LDS byte offsets for B fragments ----
    // row = n0 + l15 (n0 mult of 16) ; byte = row*256 + ((kk*64 + lg*16) ^ ((row&7)<<4))
    const int xr = (l15 & 7) << 4;
    int loff[4];
    #pragma unroll
    for (int kk = 0; kk < 4; ++kk) loff[kk] = l15 * 256 + ((kk * 64 + lg * 16) ^ xr);
    const int nwave = ch2 * 64 * 256;         // this wave's code-half base (bytes)

    float bv[2][4]; int bi[2][4];
    #pragma unroll
    for (int m = 0; m < 2; ++m)
        #pragma unroll
        for (int r = 0; r < 4; ++r) { bv[m][r] = FLT_MAX; bi[m][r] = 0; }

    // ---- prologue stage chunk 0 ----
    {
        const int o = tid * 16;               // 512 thr x 16B = 8KB per round
        #pragma unroll
        for (int r = 0; r < 4; ++r)
            gll16((const char*)g_ehi + r * 8192 + o, smem + r * 8192 + o);
        #pragma unroll
        for (int r = 0; r < 4; ++r)
            gll16((const char*)g_elo + r * 8192 + o, smem + 32768 + r * 8192 + o);
    }
    __syncthreads();

    for (int ch = 0; ch < NCHUNK; ++ch) {
        const int cb  = ch * NC;
        const int cur = ch & 1;
        // stage next chunk into the other buffer (drained by end-of-iter barrier)
        if (ch + 1 < NCHUNK) {
            const int   o  = tid * 16;
            const long  go = (long)(ch + 1) * 32768;
            char* ldst = smem + (cur ^ 1) * 65536;
            #pragma unroll
            for (int r = 0; r < 4; ++r)
                gll16((const char*)g_ehi + go + r * 8192 + o, ldst + r * 8192 + o);
            #pragma unroll
            for (int r = 0; r < 4; ++r)
                gll16((const char*)g_elo + go + r * 8192 + o, ldst + 32768 + r * 8192 + o);
        }

        const char* bhi = smem + cur * 65536 + nwave;
        const char* blo = bhi + 32768;

        #pragma unroll
        for (int n = 0; n < 4; ++n) {
            bf16x8 bh[4], bl[4];
            #pragma unroll
            for (int kk = 0; kk < 4; ++kk) {
                bh[kk] = *(const bf16x8*)(bhi + n * 4096 + loff[kk]);
                bl[kk] = *(const bf16x8*)(blo + n * 4096 + loff[kk]);
            }
            f32x4 acc[2];
            #pragma unroll
            for (int m = 0; m < 2; ++m) {
                f32x4 a = {0.f, 0.f, 0.f, 0.f};
                #pragma unroll
                for (int kk = 0; kk < 4; ++kk) {
                    a = __builtin_amdgcn_mfma_f32_16x16x32_bf16(ah[m][kk], bh[kk], a, 0, 0, 0);
                    a = __builtin_amdgcn_mfma_f32_16x16x32_bf16(al[m][kk], bh[kk], a, 0, 0, 0);
                    a = __builtin_amdgcn_mfma_f32_16x16x32_bf16(ah[m][kk], bl[kk], a, 0, 0, 0);
                }
                acc[m] = a;
            }
            // fused running argmin: score = h_c - z.e ; C layout row=(lg)*4+r, col=l15
            const int c  = cb + ch2 * 64 + n * 16 + l15;
            const float hc = g_h[c];
            #pragma unroll
            for (int m = 0; m < 2; ++m)
                #pragma unroll
                for (int r = 0; r < 4; ++r) {
                    float sc = hc - acc[m][r];
                    if (sc < bv[m][r]) { bv[m][r] = sc; bi[m][r] = c; }  // ascending scan: strict <
                }
        }
        __syncthreads();   // drains this wave's gll issues (vmcnt 0) + all waves done reading cur
    }

    // ---- argmin reduce across the 16-lane column group ----
    #pragma unroll
    for (int m = 0; m < 2; ++m)
        #pragma unroll
        for (int r = 0; r < 4; ++r) {
            float v = bv[m][r]; int ix = bi[m][r];
            #pragma unroll
            for (int o = 1; o < 16; o <<= 1) {
                float ov = __shfl_xor(v, o);
                int   oi = __shfl_xor(ix, o);
                if (ov < v || (ov == v && oi < ix)) { v = ov; ix = oi; }
            }
            if (l15 == 0) {
                int t = tq * 32 + m * 16 + lg * 4 + r;
                rv[t * 2 + ch2] = v; ri[t * 2 + ch2] = ix;
            }
        }
    __syncthreads();
    if (tid < BT) {
        float v0 = rv[tid * 2], v1 = rv[tid * 2 + 1];
        int   i0 = ri[tid * 2], i1 = ri[tid * 2 + 1];
        int best = (v1 < v0 || (v1 == v0 && i1 < i0)) ? i1 : i0;
        idx_sh[tid] = best;
        atomicAdd(&g_counts[best], 1u);
    }
    __syncthreads();

    // ---- epilogue: gather e[idx], out = z + (zq - z), loss partial ----
    float lsum = 0.f;
    {
        const float4* zf4 = (const float4*)(z + t0 * DIM);
        const float4* ef4 = (const float4*)emb;
        float4*       of4 = (float4*)(out + t0 * DIM);
        #pragma unroll
        for (int r = 0; r < 8; ++r) {
            int f = r * 512 + tid;
            int t = f >> 5, dw = f & 31;
            int ci = idx_sh[t];
            float4 e4 = ef4[(size_t)ci * 32 + dw];
            float4 z4 = zf4[f];
            float dx = e4.x - z4.x, dy = e4.y - z4.y;
            float dz = e4.z - z4.z, dw2 = e4.w - z4.w;
            lsum += dx * dx + dy * dy + dz * dz + dw2 * dw2;
            float4 o;
            o.x = z4.x + dx; o.y = z4.y + dy; o.z = z4.z + dz; o.w = z4.w + dw2;
            of4[f] = o;
        }
    }
    #pragma unroll
    for (int o = 32; o > 0; o >>= 1) lsum += __shfl_down(lsum, o);
    if (lane == 0) wred[wid] = (double)lsum;
    __syncthreads();
    if (tid == 0) {
        double s = 0.0;
        #pragma unroll
        for (int w = 0; w < 8; ++w) s += wred[w];
        atomicAdd(&g_loss, s);
    }
}

// ---------------- final: perplexity + commit loss ----------------
__global__ __launch_bounds__(256) void vq_final(float* __restrict__ out, int n_elems, int n_tok)
{
    __shared__ double sh[4];
    const int tid = threadIdx.x;
    double s = 0.0;
    for (int i = tid; i < KCB; i += 256) {
        float em = (float)g_counts[i] / (float)n_tok;
        s += (double)(em * logf(em + 1e-8f));
    }
    #pragma unroll
    for (int o = 32; o > 0; o >>= 1) s += __shfl_down(s, o);
    if ((tid & 63) == 0) sh[tid >> 6] = s;
    __syncthreads();
    if (tid == 0) {
        double tot = sh[0] + sh[1] + sh[2] + sh[3];
        out[(size_t)n_elems]     = (float)(1.25 * g_loss / (double)n_elems);
        out[(size_t)n_elems + 1] = expf((float)(-tot));
    }
}

extern "C" void kernel_launch(void* const* d_in, const int* in_sizes, int n_in,
                              void* d_out, int out_size, void* d_ws, size_t ws_size,
                              hipStream_t stream)
{
    const float* z   = (const float*)d_in[0];
    const float* emb = (const float*)d_in[1];
    float* out = (float*)d_out;

    const int n_elems = in_sizes[0];        // 4194304
    const int ntok    = n_elems / DIM;      // 32768

    vq_prep <<<dim3(KCB / 4),   256, 0, stream>>>(emb);
    vq_main <<<dim3(ntok / BT), 512, 0, stream>>>(z, emb, out);
    vq_final<<<dim3(1),         256, 0, stream>>>(out, n_elems, ntok);
}